// Round 10
// baseline (238.994 us; speedup 1.0000x reference)
//
#include <hip/hip_runtime.h>

// Problem constants (from reference)
constexpr int C   = 4096;   // HIDDEN_DIM
constexpr int NE  = 4;      // EXPANSION
constexpr int B   = 4096;   // batch rows
constexpr int THREADS = 256;          // 4 waves per block, one ROW per WAVE
constexpr int NCHUNK = C / (64 * 8);  // 8 chunks of 512 columns per row
constexpr float EPSV = 1e-5f;

// Manual RNE round-to-bf16-and-back (value-based)
__device__ inline float bf16_rne(float f) {
    unsigned int u = __float_as_uint(f);
    unsigned int r = (u + 0x7FFFu + ((u >> 16) & 1u)) & 0xFFFF0000u;
    return __uint_as_float(r);
}

// Wave-autonomous kernel: one row per wave, ZERO barriers, no LDS.
// Pass 1: stream row, per-lane ss, wave butterfly reduce.
// Pass 2: re-read row (L2/L3-hot), compute outputs, store.
__global__ __launch_bounds__(THREADS, 4)
void mhc_wave(const float* __restrict__ x,
              const float* __restrict__ w,   // rmsnorm_weight stored as f32 on device
              const float* __restrict__ Hpre,
              const float* __restrict__ Hpost,
              const float* __restrict__ Hres,
              float* __restrict__ out) {
    const int lane = threadIdx.x & 63;
    const int row  = blockIdx.x * (THREADS / 64) + (threadIdx.x >> 6);
    const float* xrow = x   + (size_t)row * (NE * C);
    float*       orow = out + (size_t)row * (NE * C);

    // ---- per-wave Sinkhorn: lanes<16 hold M[i][j], i=lane>>2, j=lane&3 ----
    // Row sums: xor 1,2 (within 4-lane j-group). Col sums: xor 4,8.
    // Lanes 16..63 carry 0 through the butterfly (0/eps = 0, harmless).
    float m = (lane < 16) ? expf(Hres[lane]) : 0.0f;
    for (int it = 0; it < 20; ++it) {
        float r = m + __shfl_xor(m, 1);
        r += __shfl_xor(r, 2);
        m /= fmaxf(r, EPSV);
        float cs = m + __shfl_xor(m, 4);
        cs += __shfl_xor(cs, 8);
        m /= fmaxf(cs, EPSV);
    }
    float M[NE * NE];
    #pragma unroll
    for (int k = 0; k < NE * NE; ++k) M[k] = __shfl(m, k);

    // ---- gates (uniform scalar loads) ----
    const float s0 = 1.0f / (1.0f + expf(-Hpre[0]));
    const float s1 = 1.0f / (1.0f + expf(-Hpre[1]));
    const float s2 = 1.0f / (1.0f + expf(-Hpre[2]));
    const float s3 = 1.0f / (1.0f + expf(-Hpre[3]));
    float hp[NE];
    #pragma unroll
    for (int i = 0; i < NE; ++i) hp[i] = 2.0f / (1.0f + expf(-Hpost[i]));

    // ---- pass 1: stream row, accumulate sum of squares of bf16-rounded agg ----
    float ss = 0.0f;
    #pragma unroll
    for (int c = 0; c < NCHUNK; ++c) {
        const int off = c * 512 + lane * 8;
        float xv[NE][8];
        #pragma unroll
        for (int k = 0; k < NE; ++k) {
            const float4* p = reinterpret_cast<const float4*>(xrow + k * C + off);
            float4 a = p[0], bq = p[1];
            xv[k][0] = a.x;  xv[k][1] = a.y;  xv[k][2] = a.z;  xv[k][3] = a.w;
            xv[k][4] = bq.x; xv[k][5] = bq.y; xv[k][6] = bq.z; xv[k][7] = bq.w;
        }
        #pragma unroll
        for (int e = 0; e < 8; ++e) {
            float a = s0 * xv[0][e] + s1 * xv[1][e] + s2 * xv[2][e] + s3 * xv[3][e];
            float abf = bf16_rne(a);
            ss += abf * abf;
        }
    }

    // ---- wave-internal butterfly reduction (64 lanes, no barrier) ----
    #pragma unroll
    for (int off = 32; off > 0; off >>= 1) ss += __shfl_xor(ss, off);

    const float rinv = 1.0f / sqrtf(ss * (1.0f / (float)C) + EPSV);

    // ---- pass 2: re-read row (cache-hot), compute outputs, store ----
    #pragma unroll
    for (int c = 0; c < NCHUNK; ++c) {
        const int off = c * 512 + lane * 8;
        float xv[NE][8];
        #pragma unroll
        for (int k = 0; k < NE; ++k) {
            const float4* p = reinterpret_cast<const float4*>(xrow + k * C + off);
            float4 a = p[0], bq = p[1];
            xv[k][0] = a.x;  xv[k][1] = a.y;  xv[k][2] = a.z;  xv[k][3] = a.w;
            xv[k][4] = bq.x; xv[k][5] = bq.y; xv[k][6] = bq.z; xv[k][7] = bq.w;
        }
        // w for this chunk (L1/L2-hot: same 16 KB reused by all rows)
        const float4* pw = reinterpret_cast<const float4*>(w + off);
        float4 w0 = pw[0], w1 = pw[1];
        float wf[8] = { w0.x, w0.y, w0.z, w0.w, w1.x, w1.y, w1.z, w1.w };

        float y[8];
        #pragma unroll
        for (int e = 0; e < 8; ++e) {
            float a = s0 * xv[0][e] + s1 * xv[1][e] + s2 * xv[2][e] + s3 * xv[3][e];
            y[e] = bf16_rne(a) * rinv * wf[e];
        }
        #pragma unroll
        for (int i = 0; i < NE; ++i) {
            float o[8];
            #pragma unroll
            for (int e = 0; e < 8; ++e) {
                o[e] = M[i * NE + 0] * xv[0][e] + M[i * NE + 1] * xv[1][e]
                     + M[i * NE + 2] * xv[2][e] + M[i * NE + 3] * xv[3][e]
                     + hp[i] * y[e];
            }
            float4* po = reinterpret_cast<float4*>(orow + i * C + off);
            po[0] = make_float4(o[0], o[1], o[2], o[3]);
            po[1] = make_float4(o[4], o[5], o[6], o[7]);
        }
    }
}

extern "C" void kernel_launch(void* const* d_in, const int* in_sizes, int n_in,
                              void* d_out, int out_size, void* d_ws, size_t ws_size,
                              hipStream_t stream) {
    const float* x     = (const float*)d_in[0];
    const float* w     = (const float*)d_in[1];   // f32 on device (np has no bf16)
    const float* Hpre  = (const float*)d_in[2];
    const float* Hpost = (const float*)d_in[3];
    const float* Hres  = (const float*)d_in[4];
    float* out         = (float*)d_out;

    mhc_wave<<<B / (THREADS / 64), THREADS, 0, stream>>>(x, w, Hpre, Hpost, Hres, out);
}

// Round 11
// 110.793 us; speedup vs baseline: 2.1571x; 2.1571x over previous
//
#include <hip/hip_runtime.h>

// Problem constants (from reference)
constexpr int C   = 4096;   // HIDDEN_DIM
constexpr int NE  = 4;      // EXPANSION
constexpr int B   = 4096;   // batch rows
constexpr int THREADS = 512;
constexpr int PER = C / THREADS;  // 8 columns per thread
constexpr int RPB = 4;            // rows per block (software pipeline depth)
constexpr float EPSV = 1e-5f;

// Manual RNE round-to-bf16-and-back (value-based)
__device__ inline float bf16_rne(float f) {
    unsigned int u = __float_as_uint(f);
    unsigned int r = (u + 0x7FFFu + ((u >> 16) & 1u)) & 0xFFFF0000u;
    return __uint_as_float(r);
}

__device__ __forceinline__ void load_row(const float* __restrict__ xrow, int c0,
                                         float (&xs)[NE][PER]) {
    #pragma unroll
    for (int k = 0; k < NE; ++k) {
        const float4* p = reinterpret_cast<const float4*>(xrow + k * C + c0);
        float4 a = p[0], bq = p[1];
        xs[k][0] = a.x;  xs[k][1] = a.y;  xs[k][2] = a.z;  xs[k][3] = a.w;
        xs[k][4] = bq.x; xs[k][5] = bq.y; xs[k][6] = bq.z; xs[k][7] = bq.w;
    }
}

// Pipelined block kernel: RPB rows per block, double-buffered x registers.
// Row r+1's loads are issued BEFORE row r's barrier, so the reduce/output
// phase of row r hides the load latency of row r+1 -> continuous HBM demand.
__global__ __launch_bounds__(THREADS)
void mhc_pipe(const float* __restrict__ x,
              const float* __restrict__ w,   // rmsnorm_weight stored as f32 on device
              const float* __restrict__ Hpre,
              const float* __restrict__ Hpost,
              const float* __restrict__ Hres,
              float* __restrict__ out) {
    const int tid  = threadIdx.x;
    const int lane = tid & 63;
    const int wid  = tid >> 6;
    const int c0   = tid * PER;
    const size_t blockbase = (size_t)blockIdx.x * RPB * NE * C;

    __shared__ float sM[NE * NE];
    __shared__ float red[RPB][THREADS / 64];

    // ---- wave 0: lane-parallel Sinkhorn (butterfly); published at first barrier ----
    if (tid < 64) {
        float m = (tid < 16) ? expf(Hres[tid]) : 0.0f;
        for (int it = 0; it < 20; ++it) {
            float r = m + __shfl_xor(m, 1);
            r += __shfl_xor(r, 2);
            m /= fmaxf(r, EPSV);
            float cs = m + __shfl_xor(m, 4);
            cs += __shfl_xor(cs, 8);
            m /= fmaxf(cs, EPSV);
        }
        if (tid < 16) sM[tid] = m;
    }

    // ---- gates (uniform, cheap, per-thread) ----
    const float s0 = 1.0f / (1.0f + expf(-Hpre[0]));
    const float s1 = 1.0f / (1.0f + expf(-Hpre[1]));
    const float s2 = 1.0f / (1.0f + expf(-Hpre[2]));
    const float s3 = 1.0f / (1.0f + expf(-Hpre[3]));
    float hp[NE];
    #pragma unroll
    for (int i = 0; i < NE; ++i) hp[i] = 2.0f / (1.0f + expf(-Hpost[i]));

    // ---- w slice: fixed per thread across all rows; load once into regs ----
    float wf[PER];
    {
        const float4* pw = reinterpret_cast<const float4*>(w + c0);
        float4 w0 = pw[0], w1 = pw[1];
        wf[0] = w0.x; wf[1] = w0.y; wf[2] = w0.z; wf[3] = w0.w;
        wf[4] = w1.x; wf[5] = w1.y; wf[6] = w1.z; wf[7] = w1.w;
    }

    float xsA[NE][PER], xsB[NE][PER];
    float M[NE * NE];

    // ---- one pipeline step (inlined with literal r -> everything static) ----
    auto step = [&](int r, float (&cur)[NE][PER], float (&nxt)[NE][PER]) {
        // sum of squares of bf16-rounded aggregate (consumes cur's loads)
        float ss = 0.0f;
        #pragma unroll
        for (int c = 0; c < PER; ++c) {
            float a = s0 * cur[0][c] + s1 * cur[1][c] + s2 * cur[2][c] + s3 * cur[3][c];
            float abf = bf16_rne(a);
            ss += abf * abf;
        }

        // issue NEXT row's loads now — they fly across the barrier/output phase
        if (r + 1 < RPB)
            load_row(x + blockbase + (size_t)(r + 1) * NE * C, c0, nxt);

        // block reduction for this row (private red slot per r: no WAR barrier)
        #pragma unroll
        for (int off = 32; off > 0; off >>= 1) ss += __shfl_xor(ss, off);
        if (lane == 0) red[r][wid] = ss;
        __syncthreads();                    // r==0: also publishes sM

        if (r == 0) {
            #pragma unroll
            for (int k = 0; k < NE * NE; ++k) M[k] = sM[k];
        }

        float tot = 0.0f;
        #pragma unroll
        for (int i = 0; i < THREADS / 64; ++i) tot += red[r][i];
        const float rinv = 1.0f / sqrtf(tot * (1.0f / (float)C) + EPSV);

        // outputs for this row (recompute agg per element; y = agg_bf*rinv*w)
        float* orow = out + blockbase + (size_t)r * NE * C;
        float y[PER];
        #pragma unroll
        for (int c = 0; c < PER; ++c) {
            float a = s0 * cur[0][c] + s1 * cur[1][c] + s2 * cur[2][c] + s3 * cur[3][c];
            y[c] = bf16_rne(a) * rinv * wf[c];
        }
        #pragma unroll
        for (int i = 0; i < NE; ++i) {
            float o[PER];
            #pragma unroll
            for (int c = 0; c < PER; ++c) {
                o[c] = M[i * NE + 0] * cur[0][c] + M[i * NE + 1] * cur[1][c]
                     + M[i * NE + 2] * cur[2][c] + M[i * NE + 3] * cur[3][c]
                     + hp[i] * y[c];
            }
            float4* po = reinterpret_cast<float4*>(orow + (size_t)i * C + c0);
            po[0] = make_float4(o[0], o[1], o[2], o[3]);
            po[1] = make_float4(o[4], o[5], o[6], o[7]);
        }
    };

    load_row(x + blockbase, c0, xsA);
    step(0, xsA, xsB);
    step(1, xsB, xsA);
    step(2, xsA, xsB);
    step(3, xsB, xsA);
}

extern "C" void kernel_launch(void* const* d_in, const int* in_sizes, int n_in,
                              void* d_out, int out_size, void* d_ws, size_t ws_size,
                              hipStream_t stream) {
    const float* x     = (const float*)d_in[0];
    const float* w     = (const float*)d_in[1];   // f32 on device (np has no bf16)
    const float* Hpre  = (const float*)d_in[2];
    const float* Hpost = (const float*)d_in[3];
    const float* Hres  = (const float*)d_in[4];
    float* out         = (float*)d_out;

    mhc_pipe<<<B / RPB, THREADS, 0, stream>>>(x, w, Hpre, Hpost, Hres, out);
}

// Round 12
// 106.164 us; speedup vs baseline: 2.2512x; 1.0436x over previous
//
#include <hip/hip_runtime.h>

// Problem constants (from reference)
constexpr int C   = 4096;   // HIDDEN_DIM
constexpr int NE  = 4;      // EXPANSION
constexpr int B   = 4096;   // batch rows
constexpr int THREADS = 512;
constexpr int RPB = 4;      // rows per block (pipeline depth)
constexpr float EPSV = 1e-5f;

// Manual RNE round-to-bf16-and-back (value-based)
__device__ inline float bf16_rne(float f) {
    unsigned int u = __float_as_uint(f);
    unsigned int r = (u + 0x7FFFu + ((u >> 16) & 1u)) & 0xFFFF0000u;
    return __uint_as_float(r);
}

__device__ __forceinline__ void ld4(const float* __restrict__ p, float (&d)[4]) {
    float4 t = *reinterpret_cast<const float4*>(p);
    d[0] = t.x; d[1] = t.y; d[2] = t.z; d[3] = t.w;
}
__device__ __forceinline__ void st4(float* __restrict__ p, const float (&d)[4]) {
    *reinterpret_cast<float4*>(p) = make_float4(d[0], d[1], d[2], d[3]);
}

// Dense-addressed pipelined kernel.
// Thread (wave w, lane l) owns cols cA = w*256 + l*4 and cB = 2048 + cA:
// every load/store instruction is a fully dense, contiguous 1 KB wave access
// (the m13-copy pattern). Prefetch of row r+1 is issued AFTER the barrier so
// the compiler's vmcnt(0)-before-s_barrier never drains it.
__global__ __launch_bounds__(THREADS)
void mhc_pipe(const float* __restrict__ x,
              const float* __restrict__ w,   // rmsnorm_weight stored as f32 on device
              const float* __restrict__ Hpre,
              const float* __restrict__ Hpost,
              const float* __restrict__ Hres,
              float* __restrict__ out) {
    const int tid  = threadIdx.x;
    const int lane = tid & 63;
    const int wid  = tid >> 6;
    const int cA   = wid * 256 + lane * 4;
    const int cB   = 2048 + cA;
    const size_t blockbase = (size_t)blockIdx.x * RPB * NE * C;

    __shared__ float sM[NE * NE];
    __shared__ float red[RPB][THREADS / 64];

    // ---- wave 0: lane-parallel Sinkhorn (butterfly); published at first barrier ----
    if (tid < 64) {
        float m = (tid < 16) ? expf(Hres[tid]) : 0.0f;
        for (int it = 0; it < 20; ++it) {
            float r = m + __shfl_xor(m, 1);
            r += __shfl_xor(r, 2);
            m /= fmaxf(r, EPSV);
            float cs = m + __shfl_xor(m, 4);
            cs += __shfl_xor(cs, 8);
            m /= fmaxf(cs, EPSV);
        }
        if (tid < 16) sM[tid] = m;
    }

    // ---- gates (uniform, cheap, per-thread) ----
    const float s0 = 1.0f / (1.0f + expf(-Hpre[0]));
    const float s1 = 1.0f / (1.0f + expf(-Hpre[1]));
    const float s2 = 1.0f / (1.0f + expf(-Hpre[2]));
    const float s3 = 1.0f / (1.0f + expf(-Hpre[3]));
    float hp[NE];
    #pragma unroll
    for (int i = 0; i < NE; ++i) hp[i] = 2.0f / (1.0f + expf(-Hpost[i]));

    // ---- w slices (fixed per thread; L2-hot) ----
    float wf[2][4];
    ld4(w + cA, wf[0]);
    ld4(w + cB, wf[1]);

    // Double-buffered x registers: [stream][half][elem]
    float xsA[NE][2][4], xsB[NE][2][4];
    float M[NE * NE];

    auto load_row = [&](const float* __restrict__ xrow, float (&xs)[NE][2][4]) {
        #pragma unroll
        for (int k = 0; k < NE; ++k) {
            ld4(xrow + k * C + cA, xs[k][0]);
            ld4(xrow + k * C + cB, xs[k][1]);
        }
    };

    auto step = [&](int r, float (&cur)[NE][2][4], float (&nxt)[NE][2][4]) {
        // ---- aggregate + bf16 round + partial sum of squares (consumes cur) ----
        float aggbf[2][4];
        float ss = 0.0f;
        #pragma unroll
        for (int h = 0; h < 2; ++h)
            #pragma unroll
            for (int e = 0; e < 4; ++e) {
                float a = s0 * cur[0][h][e] + s1 * cur[1][h][e]
                        + s2 * cur[2][h][e] + s3 * cur[3][h][e];
                float abf = bf16_rne(a);
                aggbf[h][e] = abf;
                ss += abf * abf;
            }

        // ---- block reduction (nothing useful in flight at this barrier) ----
        #pragma unroll
        for (int off = 32; off > 0; off >>= 1) ss += __shfl_xor(ss, off);
        if (lane == 0) red[r][wid] = ss;
        __syncthreads();                     // r==0: also publishes sM

        if (r == 0) {
            #pragma unroll
            for (int k = 0; k < NE * NE; ++k) M[k] = sM[k];
        }

        // ---- prefetch next row NOW (post-barrier: never drained; flies over outputs) ----
        if (r + 1 < RPB)
            load_row(x + blockbase + (size_t)(r + 1) * NE * C, nxt);

        float tot = 0.0f;
        #pragma unroll
        for (int i = 0; i < THREADS / 64; ++i) tot += red[r][i];
        const float rinv = 1.0f / sqrtf(tot * (1.0f / (float)C) + EPSV);

        // ---- outputs ----
        float* orow = out + blockbase + (size_t)r * NE * C;
        float y[2][4];
        #pragma unroll
        for (int h = 0; h < 2; ++h)
            #pragma unroll
            for (int e = 0; e < 4; ++e)
                y[h][e] = aggbf[h][e] * rinv * wf[h][e];

        #pragma unroll
        for (int i = 0; i < NE; ++i) {
            float o[2][4];
            #pragma unroll
            for (int h = 0; h < 2; ++h)
                #pragma unroll
                for (int e = 0; e < 4; ++e)
                    o[h][e] = M[i * NE + 0] * cur[0][h][e] + M[i * NE + 1] * cur[1][h][e]
                            + M[i * NE + 2] * cur[2][h][e] + M[i * NE + 3] * cur[3][h][e]
                            + hp[i] * y[h][e];
            st4(orow + i * C + cA, o[0]);
            st4(orow + i * C + cB, o[1]);
        }
    };

    load_row(x + blockbase, xsA);
    step(0, xsA, xsB);
    step(1, xsB, xsA);
    step(2, xsA, xsB);
    step(3, xsB, xsA);
}

extern "C" void kernel_launch(void* const* d_in, const int* in_sizes, int n_in,
                              void* d_out, int out_size, void* d_ws, size_t ws_size,
                              hipStream_t stream) {
    const float* x     = (const float*)d_in[0];
    const float* w     = (const float*)d_in[1];   // f32 on device (np has no bf16)
    const float* Hpre  = (const float*)d_in[2];
    const float* Hpost = (const float*)d_in[3];
    const float* Hres  = (const float*)d_in[4];
    float* out         = (float*)d_out;

    mhc_pipe<<<B / RPB, THREADS, 0, stream>>>(x, w, Hpre, Hpost, Hres, out);
}